// Round 1
// baseline (251.837 us; speedup 1.0000x reference)
//
#include <hip/hip_runtime.h>

#define DIM   1024
#define NQKV  3072
#define SEQ   2048
#define HEADS 16
#define DHEAD 64
#define M_TOT 4096   // batch(2) * seq(2048)

typedef __bf16 bf16;
typedef __bf16 bf16x8 __attribute__((ext_vector_type(8)));
typedef float  f32x4  __attribute__((ext_vector_type(4)));

static __device__ __forceinline__ unsigned short f2b(float f) {
    bf16 h = (bf16)f;
    return __builtin_bit_cast(unsigned short, h);
}

// ---------------- kernel 1: cast x fp32 -> bf16 ----------------
__global__ void cast_x_kernel(const float* __restrict__ x,
                              unsigned short* __restrict__ xb, int n) {
    int i = (blockIdx.x * blockDim.x + threadIdx.x) * 4;
    if (i < n) {
        float4 v = *(const float4*)(x + i);
        ushort4 o;
        o.x = f2b(v.x); o.y = f2b(v.y); o.z = f2b(v.z); o.w = f2b(v.w);
        *(ushort4*)(xb + i) = o;
    }
}

// ---------------- kernel 2: transpose+cast W [K][N] -> Wt [N][K] bf16 ----------------
__global__ void transpose_w_kernel(const float* __restrict__ W,
                                   unsigned short* __restrict__ Wt) {
    __shared__ float tile[32][33];
    int nb = blockIdx.x;   // 0..95  (N tiles)
    int kb = blockIdx.y;   // 0..31  (K tiles)
    int tx = threadIdx.x;  // 0..31
    for (int ty = threadIdx.y; ty < 32; ty += 8)
        tile[ty][tx] = W[(size_t)(kb*32 + ty)*NQKV + nb*32 + tx];
    __syncthreads();
    for (int ty = threadIdx.y; ty < 32; ty += 8)
        Wt[(size_t)(nb*32 + ty)*DIM + kb*32 + tx] = f2b(tile[tx][ty]);
}

// ---------------- kernel 3: QKV GEMM ----------------
// A = xb [4096][1024] bf16, Bt = Wt [3072][1024] bf16.
// Writes Q,K as [bh][n][d] bf16 and V transposed as [bh][d][n] bf16.
#define LDA 72   // 64 + 8 pad -> row stride 144B, 16B-aligned, 2-way LDS conflicts (free)
__global__ __launch_bounds__(256) void qkv_gemm_kernel(
    const unsigned short* __restrict__ A,
    const unsigned short* __restrict__ Bt,
    unsigned short* __restrict__ Qw,
    unsigned short* __restrict__ Kw,
    unsigned short* __restrict__ Vtw)
{
    __shared__ __align__(16) unsigned short As[128 * LDA];
    __shared__ __align__(16) unsigned short Bs[128 * LDA];
    const int tid  = threadIdx.x;
    const int m0   = blockIdx.y * 128;
    const int n0   = blockIdx.x * 128;
    const int w    = tid >> 6;
    const int lane = tid & 63;
    const int l16  = lane & 15;
    const int quad = lane >> 4;
    const int wm   = (w >> 1) * 64;
    const int wn   = (w & 1) * 64;

    f32x4 acc[4][4];
    const f32x4 fzero = {0.f, 0.f, 0.f, 0.f};
    for (int i = 0; i < 4; i++)
        for (int j = 0; j < 4; j++) acc[i][j] = fzero;

    for (int kt = 0; kt < DIM; kt += 64) {
        // stage A-tile 128x64 and Bt-tile 128x64 (16B chunks, coalesced)
        #pragma unroll
        for (int i = 0; i < 4; i++) {
            int c = tid + i * 256;           // 0..1023
            int row = c >> 3, col = (c & 7) * 8;
            uint4 va = *(const uint4*)(A  + (size_t)(m0 + row) * DIM + kt + col);
            *(uint4*)(&As[row * LDA + col]) = va;
            uint4 vb = *(const uint4*)(Bt + (size_t)(n0 + row) * DIM + kt + col);
            *(uint4*)(&Bs[row * LDA + col]) = vb;
        }
        __syncthreads();
        #pragma unroll
        for (int s = 0; s < 2; s++) {
            bf16x8 af[4], bfr[4];
            #pragma unroll
            for (int i = 0; i < 4; i++) {
                af[i]  = *(const bf16x8*)(&As[(wm + i * 16 + l16) * LDA + s * 32 + quad * 8]);
                bfr[i] = *(const bf16x8*)(&Bs[(wn + i * 16 + l16) * LDA + s * 32 + quad * 8]);
            }
            #pragma unroll
            for (int i = 0; i < 4; i++)
                #pragma unroll
                for (int j = 0; j < 4; j++)
                    acc[i][j] = __builtin_amdgcn_mfma_f32_16x16x32_bf16(af[i], bfr[j], acc[i][j], 0, 0, 0);
        }
        __syncthreads();
    }

    // epilogue: scatter into Q/K [bh][n][d], V^T [bh][d][n]
    for (int i = 0; i < 4; i++) {
        for (int j = 0; j < 4; j++) {
            int colj = n0 + wn + j * 16 + l16;       // 0..3071
            int part = colj >> 10;                   // 0=q 1=k 2=v
            int c    = colj & 1023;
            int h    = c >> 6, d = c & 63;
            #pragma unroll
            for (int r = 0; r < 4; r++) {
                int m  = m0 + wm + i * 16 + quad * 4 + r;  // 0..4095
                int b  = m >> 11, np = m & 2047;
                int bh = b * HEADS + h;
                unsigned short val = f2b(acc[i][j][r]);
                if (part == 0)      Qw[((size_t)bh * SEQ + np) * DHEAD + d] = val;
                else if (part == 1) Kw[((size_t)bh * SEQ + np) * DHEAD + d] = val;
                else                Vtw[((size_t)bh * DHEAD + d) * SEQ + np] = val;
            }
        }
    }
}

// ---------------- kernel 4: flash attention + residual ----------------
#define LDK 72
__global__ __launch_bounds__(256) void attn_kernel(
    const unsigned short* __restrict__ Qw,
    const unsigned short* __restrict__ Kw,
    const unsigned short* __restrict__ Vtw,
    const float* __restrict__ x,
    float* __restrict__ out)
{
    __shared__ __align__(16) unsigned short Ks[64 * LDK];
    __shared__ __align__(16) unsigned short Vs[64 * LDK];   // V^T tile: [d][key]
    __shared__ __align__(16) unsigned short Ps[4][16 * LDK];
    const int qt   = blockIdx.x;   // 0..31 q-tile
    const int bh   = blockIdx.y;   // 0..31
    const int tid  = threadIdx.x;
    const int w    = tid >> 6, lane = tid & 63;
    const int l16  = lane & 15, quad = lane >> 4;

    // Q fragments for this wave's 16 rows (A-layout: m=l16, k=quad*8+j)
    const unsigned short* Qbase = Qw + ((size_t)bh * SEQ + qt * 64 + w * 16 + l16) * DHEAD;
    bf16x8 qf[2];
    qf[0] = *(const bf16x8*)(Qbase + quad * 8);
    qf[1] = *(const bf16x8*)(Qbase + 32 + quad * 8);

    float mrow[4], lrow[4];
    f32x4 o[4];
    const f32x4 fzero = {0.f, 0.f, 0.f, 0.f};
    #pragma unroll
    for (int r = 0; r < 4; r++) { mrow[r] = -INFINITY; lrow[r] = 0.f; }
    #pragma unroll
    for (int d = 0; d < 4; d++) o[d] = fzero;

    const unsigned short* Kg = Kw  + (size_t)bh * SEQ * DHEAD;
    const unsigned short* Vg = Vtw + (size_t)bh * DHEAD * SEQ;

    for (int kv = 0; kv < SEQ; kv += 64) {
        // stage K tile [64 key][64 d] and V^T tile [64 d][64 key]
        #pragma unroll
        for (int i = 0; i < 2; i++) {
            int c = tid + i * 256;             // 0..511
            int rowi = c >> 3, col = (c & 7) * 8;
            uint4 kvv = *(const uint4*)(Kg + (size_t)(kv + rowi) * DHEAD + col);
            *(uint4*)(&Ks[rowi * LDK + col]) = kvv;
            uint4 vvv = *(const uint4*)(Vg + (size_t)rowi * SEQ + kv + col);
            *(uint4*)(&Vs[rowi * LDK + col]) = vvv;
        }
        __syncthreads();

        // S = Q K^T  (4 key-subtiles of 16)
        f32x4 sacc[4];
        #pragma unroll
        for (int ki = 0; ki < 4; ki++) {
            sacc[ki] = fzero;
            #pragma unroll
            for (int s = 0; s < 2; s++) {
                bf16x8 kf = *(const bf16x8*)(&Ks[(ki * 16 + l16) * LDK + s * 32 + quad * 8]);
                sacc[ki] = __builtin_amdgcn_mfma_f32_16x16x32_bf16(qf[s], kf, sacc[ki], 0, 0, 0);
            }
        }

        // online softmax (rows quad*4+r, replicated across the 16 lanes of the quad-group)
        float pv[4][4];
        #pragma unroll
        for (int r = 0; r < 4; r++) {
            float s0 = sacc[0][r] * 0.125f, s1 = sacc[1][r] * 0.125f;
            float s2 = sacc[2][r] * 0.125f, s3 = sacc[3][r] * 0.125f;
            float mt = fmaxf(fmaxf(s0, s1), fmaxf(s2, s3));
            #pragma unroll
            for (int off = 1; off < 16; off <<= 1)
                mt = fmaxf(mt, __shfl_xor(mt, off, 64));
            float mnew  = fmaxf(mrow[r], mt);
            float alpha = __expf(mrow[r] - mnew);
            mrow[r] = mnew;
            float p0 = __expf(s0 - mnew), p1 = __expf(s1 - mnew);
            float p2 = __expf(s2 - mnew), p3 = __expf(s3 - mnew);
            pv[0][r] = p0; pv[1][r] = p1; pv[2][r] = p2; pv[3][r] = p3;
            float rs = p0 + p1 + p2 + p3;
            #pragma unroll
            for (int off = 1; off < 16; off <<= 1)
                rs += __shfl_xor(rs, off, 64);
            lrow[r] = lrow[r] * alpha + rs;
            #pragma unroll
            for (int d = 0; d < 4; d++) o[d][r] *= alpha;
        }

        // P: C-layout -> A-layout via per-wave LDS round-trip (bf16)
        #pragma unroll
        for (int ki = 0; ki < 4; ki++)
            #pragma unroll
            for (int r = 0; r < 4; r++)
                Ps[w][(quad * 4 + r) * LDK + ki * 16 + l16] = f2b(pv[ki][r]);

        // O += P V   (V^T tile gives B-frag as contiguous 16B reads)
        #pragma unroll
        for (int s = 0; s < 2; s++) {
            bf16x8 pf = *(const bf16x8*)(&Ps[w][l16 * LDK + s * 32 + quad * 8]);
            #pragma unroll
            for (int d = 0; d < 4; d++) {
                bf16x8 vf = *(const bf16x8*)(&Vs[(d * 16 + l16) * LDK + s * 32 + quad * 8]);
                o[d] = __builtin_amdgcn_mfma_f32_16x16x32_bf16(pf, vf, o[d], 0, 0, 0);
            }
        }
        __syncthreads();
    }

    // epilogue: normalize, add residual, store fp32
    const int b = bh >> 4, h = bh & 15;
    #pragma unroll
    for (int di = 0; di < 4; di++) {
        #pragma unroll
        for (int r = 0; r < 4; r++) {
            int np  = qt * 64 + w * 16 + quad * 4 + r;
            int col = h * 64 + di * 16 + l16;
            size_t g = ((size_t)(b * SEQ + np)) * DIM + col;
            out[g] = o[di][r] / lrow[r] + x[g];
        }
    }
}

extern "C" void kernel_launch(void* const* d_in, const int* in_sizes, int n_in,
                              void* d_out, int out_size, void* d_ws, size_t ws_size,
                              hipStream_t stream) {
    const float* x  = (const float*)d_in[0];   // [2,2048,1024]
    const float* Wq = (const float*)d_in[1];   // [1024,3072]
    float* out = (float*)d_out;

    unsigned short* xb = (unsigned short*)d_ws;                  // [4096][1024]
    unsigned short* Wt = xb + (size_t)M_TOT * DIM;               // [3072][1024]
    unsigned short* Qw = Wt + (size_t)NQKV * DIM;                // [32][2048][64]
    unsigned short* Kw = Qw + (size_t)32 * SEQ * DHEAD;          // [32][2048][64]
    unsigned short* Vt = Kw + (size_t)32 * SEQ * DHEAD;          // [32][64][2048]

    int nx = M_TOT * DIM;
    cast_x_kernel<<<nx / (256 * 4), 256, 0, stream>>>(x, xb, nx);
    transpose_w_kernel<<<dim3(NQKV / 32, DIM / 32), dim3(32, 8), 0, stream>>>(Wq, Wt);
    qkv_gemm_kernel<<<dim3(NQKV / 128, M_TOT / 128), 256, 0, stream>>>(xb, Wt, Qw, Kw, Vt);
    attn_kernel<<<dim3(SEQ / 64, 32), 256, 0, stream>>>(Qw, Kw, Vt, x, out);
}